// Round 1
// baseline (1388.096 us; speedup 1.0000x reference)
//
#include <hip/hip_runtime.h>
#include <hip/hip_bf16.h>
#include <stdint.h>
#include <stddef.h>

#define NW    4096
#define LSEQ  24
#define HDIM  512
#define DWG   300
#define DCC   128
#define VCC   100
#define G4H   2048
#define CATD  812
#define HIDD  512
#define NOUT  5

typedef __bf16 bf16x8 __attribute__((ext_vector_type(8)));
typedef float  f32x16 __attribute__((ext_vector_type(16)));

__device__ __forceinline__ float sigf(float x) { return 1.0f / (1.0f + __expf(-x)); }
__device__ __forceinline__ float tanh_fast(float x) { return 2.0f / (1.0f + __expf(-2.0f * x)) - 1.0f; }

// ---------------- prep: W_hh f32 -> bf16 (same [2048][512] row-major layout) ----------------
__global__ void k_convert_whh(const float* __restrict__ w, __hip_bfloat16* __restrict__ o) {
    const int i = (blockIdx.x * blockDim.x + threadIdx.x) * 4;
    const float4 v = *reinterpret_cast<const float4*>(w + i);
    o[i + 0] = __float2bfloat16(v.x);
    o[i + 1] = __float2bfloat16(v.y);
    o[i + 2] = __float2bfloat16(v.z);
    o[i + 3] = __float2bfloat16(v.w);
}

// ---------------- prep: char_proj[c][j] = char_embed[c,:] @ W_ih[j,:] + b_ih[j] + b_hh[j] ----
__global__ void k_char_proj(const float* __restrict__ cemb, const float* __restrict__ wih,
                            const float* __restrict__ bih, const float* __restrict__ bhh,
                            float* __restrict__ cproj) {
    __shared__ float emb[DCC];
    const int c = blockIdx.x;
    if (threadIdx.x < DCC) emb[threadIdx.x] = cemb[c * DCC + threadIdx.x];
    __syncthreads();
    for (int j = threadIdx.x; j < G4H; j += blockDim.x) {
        const float* w = wih + (size_t)j * DCC;
        float acc = bih[j] + bhh[j];
#pragma unroll 4
        for (int k = 0; k < DCC; ++k) acc = fmaf(emb[k], w[k], acc);
        cproj[(size_t)c * G4H + j] = acc;
    }
}

// ---------------- LSTM step: gates = h @ W_hh^T (MFMA) + char_proj gather; fused update -----
// grid 256 blocks (16 rowgroups x 16 colgroups via XCD-aware remap), 256 threads = 4 waves.
// Each wave: 2 row-tiles(32) x 4 gate-tiles(32) of mfma_f32_32x32x16_bf16 over K=512.
__launch_bounds__(256, 1)
__global__ void k_lstm_step(const __hip_bfloat16* __restrict__ hprev,
                            __hip_bfloat16* __restrict__ hnext,
                            float* __restrict__ cstate,
                            const __hip_bfloat16* __restrict__ wbf,   // [2048][512] bf16
                            const float* __restrict__ cproj,          // [100][2048] f32
                            const int* __restrict__ cidx,             // [NW][LSEQ]
                            const int* __restrict__ clen,             // [NW]
                            int t) {
    // XCD-aware remap: dispatch round-robins bid%8 across XCDs; give each XCD 2 rowgroups
    // so its h working set is 512KB (L2-resident) instead of all 4MB.
    const int b = blockIdx.x;
    const int xcd = b & 7, slot = b >> 3;
    const int rg = xcd * 2 + (slot >> 4);   // 0..15
    const int cg = slot & 15;               // 0..15

    const int wave = threadIdx.x >> 6;
    const int lane = threadIdx.x & 63;
    const int l31 = lane & 31;
    const int lhi = lane >> 5;

    const int r0 = rg * 256 + wave * 64;    // this wave: rows r0..r0+63 (2 tiles of 32)
    const int c0 = cg * 32;                 // h-cols c0..c0+31

    f32x16 acc[2][4] = {};

    // A frag: a[i] = h[r0 + rt*32 + (lane&31)][k0 + (lane>>5)*8 + i]
    const __hip_bfloat16* arow0 = hprev + (size_t)(r0 + l31) * HDIM + lhi * 8;
    const __hip_bfloat16* arow1 = arow0 + 32 * HDIM;
    // B frag: b[i] = W[g*512 + c0 + (lane&31)][k0 + (lane>>5)*8 + i]  (B[k][j] = W[j][k])
    const __hip_bfloat16* bbase = wbf + (size_t)(c0 + l31) * HDIM + lhi * 8;

#pragma unroll 2
    for (int k0 = 0; k0 < HDIM; k0 += 16) {
        const bf16x8 a0 = *reinterpret_cast<const bf16x8*>(arow0 + k0);
        const bf16x8 a1 = *reinterpret_cast<const bf16x8*>(arow1 + k0);
        const bf16x8 b0 = *reinterpret_cast<const bf16x8*>(bbase + k0);
        const bf16x8 b1 = *reinterpret_cast<const bf16x8*>(bbase + 512 * HDIM + k0);
        const bf16x8 b2 = *reinterpret_cast<const bf16x8*>(bbase + 1024 * HDIM + k0);
        const bf16x8 b3 = *reinterpret_cast<const bf16x8*>(bbase + 1536 * HDIM + k0);
        acc[0][0] = __builtin_amdgcn_mfma_f32_32x32x16_bf16(a0, b0, acc[0][0], 0, 0, 0);
        acc[1][0] = __builtin_amdgcn_mfma_f32_32x32x16_bf16(a1, b0, acc[1][0], 0, 0, 0);
        acc[0][1] = __builtin_amdgcn_mfma_f32_32x32x16_bf16(a0, b1, acc[0][1], 0, 0, 0);
        acc[1][1] = __builtin_amdgcn_mfma_f32_32x32x16_bf16(a1, b1, acc[1][1], 0, 0, 0);
        acc[0][2] = __builtin_amdgcn_mfma_f32_32x32x16_bf16(a0, b2, acc[0][2], 0, 0, 0);
        acc[1][2] = __builtin_amdgcn_mfma_f32_32x32x16_bf16(a1, b2, acc[1][2], 0, 0, 0);
        acc[0][3] = __builtin_amdgcn_mfma_f32_32x32x16_bf16(a0, b3, acc[0][3], 0, 0, 0);
        acc[1][3] = __builtin_amdgcn_mfma_f32_32x32x16_bf16(a1, b3, acc[1][3], 0, 0, 0);
    }

    // Epilogue: C/D layout (verified): col = lane&31, row = (reg&3) + 8*(reg>>2) + 4*(lane>>5)
    const int colh = c0 + l31;
#pragma unroll
    for (int rt = 0; rt < 2; ++rt) {
#pragma unroll
        for (int reg = 0; reg < 16; ++reg) {
            const int rin = (reg & 3) + 8 * (reg >> 2) + 4 * lhi;
            const int n = r0 + rt * 32 + rin;
            const int ci = cidx[n * LSEQ + t];
            const int len = clen[n];
            const float* cp = cproj + (size_t)ci * G4H + colh;
            const float gi = acc[rt][0][reg] + cp[0];
            const float gf = acc[rt][1][reg] + cp[512];
            const float gg = acc[rt][2][reg] + cp[1024];
            const float go = acc[rt][3][reg] + cp[1536];
            const size_t off = (size_t)n * HDIM + colh;
            const float c_old = cstate[off];
            const float i_s = sigf(gi);
            const float f_s = sigf(gf);
            const float g_t = tanh_fast(gg);
            const float o_s = sigf(go);
            const float c_new = f_s * c_old + i_s * g_t;
            const float h_new = o_s * tanh_fast(c_new);
            const bool valid = (t < len);
            if (valid) cstate[off] = c_new;
            hnext[off] = valid ? __float2bfloat16(h_new) : hprev[off];
        }
    }
}

// ---------------- masked column sums of final h (len>=2), 8x8 partial grid ----------------
__global__ void k_sum_char(const __hip_bfloat16* __restrict__ h, const int* __restrict__ clen,
                           float* __restrict__ pchar) {
    const int col = blockIdx.x * 64 + (threadIdx.x & 63);
    const int phase = threadIdx.x >> 6;
    const int nbase = blockIdx.y * 512;
    float s = 0.0f;
    for (int n = nbase + phase; n < nbase + 512; n += 4) {
        if (clen[n] >= 2) s += __bfloat162float(h[(size_t)n * HDIM + col]);
    }
    __shared__ float red[256];
    red[threadIdx.x] = s;
    __syncthreads();
    if (phase == 0) {
        pchar[blockIdx.y * HDIM + col] =
            red[threadIdx.x] + red[threadIdx.x + 64] + red[threadIdx.x + 128] + red[threadIdx.x + 192];
    }
}

// ---------------- glove gather column sums, 5x8 partial grid ----------------
__global__ void k_sum_glove(const float* __restrict__ gt, const int* __restrict__ widx,
                            float* __restrict__ pglove) {
    const int col = blockIdx.x * 64 + (threadIdx.x & 63);
    const int phase = threadIdx.x >> 6;
    const int nbase = blockIdx.y * 512;
    float s = 0.0f;
    if (col < DWG) {
        for (int n = nbase + phase; n < nbase + 512; n += 4) {
            s += gt[(size_t)widx[n] * DWG + col];
        }
    }
    __shared__ float red[256];
    red[threadIdx.x] = s;
    __syncthreads();
    if (phase == 0 && col < DWG) {
        pglove[blockIdx.y * DWG + col] =
            red[threadIdx.x] + red[threadIdx.x + 64] + red[threadIdx.x + 128] + red[threadIdx.x + 192];
    }
}

// ---------------- head: avg -> sigmoid(fc1) -> fc2 ----------------
__global__ void k_head(const float* __restrict__ pglove, const float* __restrict__ pchar,
                       const float* __restrict__ fc1W, const float* __restrict__ fc1b,
                       const float* __restrict__ fc2W, const float* __restrict__ fc2b,
                       float* __restrict__ out) {
    __shared__ float avg[CATD];
    __shared__ float h1[HIDD];
    const int tid = threadIdx.x;
    for (int i = tid; i < CATD; i += 512) {
        float s = 0.0f;
        if (i < DWG) {
            for (int r = 0; r < 8; ++r) s += pglove[r * DWG + i];
        } else {
            const int c = i - DWG;
            for (int r = 0; r < 8; ++r) s += pchar[r * HDIM + c];
        }
        avg[i] = s * (1.0f / 4096.0f);
    }
    __syncthreads();
    {
        const float* w = fc1W + (size_t)tid * CATD;
        float acc = fc1b[tid];
#pragma unroll 4
        for (int k = 0; k < CATD; ++k) acc = fmaf(avg[k], w[k], acc);
        h1[tid] = sigf(acc);
    }
    __syncthreads();
    if (tid < NOUT) {
        const float* w = fc2W + (size_t)tid * HIDD;
        float acc = fc2b[tid];
#pragma unroll 4
        for (int k = 0; k < HIDD; ++k) acc = fmaf(h1[k], w[k], acc);
        out[tid] = acc;
    }
}

extern "C" void kernel_launch(void* const* d_in, const int* in_sizes, int n_in,
                              void* d_out, int out_size, void* d_ws, size_t ws_size,
                              hipStream_t stream) {
    (void)in_sizes; (void)n_in; (void)out_size; (void)ws_size;
    const int*   widx  = (const int*)d_in[0];
    const int*   cidx  = (const int*)d_in[1];
    const int*   clen  = (const int*)d_in[2];
    const float* glove = (const float*)d_in[3];
    const float* cemb  = (const float*)d_in[4];
    const float* wih   = (const float*)d_in[5];
    const float* whh   = (const float*)d_in[6];
    const float* bih   = (const float*)d_in[7];
    const float* bhh   = (const float*)d_in[8];
    const float* fc1W  = (const float*)d_in[9];
    const float* fc1b  = (const float*)d_in[10];
    const float* fc2W  = (const float*)d_in[11];
    const float* fc2b  = (const float*)d_in[12];
    float* out = (float*)d_out;

    char* ws = (char*)d_ws;
    __hip_bfloat16* wbf    = (__hip_bfloat16*)(ws);                     // 2 MB
    float*          cproj  = (float*)(ws + (2u  << 20));                // 800 KB
    __hip_bfloat16* h0     = (__hip_bfloat16*)(ws + (3u  << 20));       // 4 MB
    __hip_bfloat16* h1buf  = (__hip_bfloat16*)(ws + (7u  << 20));       // 4 MB
    float*          cst    = (float*)(ws + (11u << 20));                // 8 MB
    float*          pchar  = (float*)(ws + (19u << 20));                // 8*512*4
    float*          pglove = (float*)(ws + (19u << 20) + 16384);        // 8*300*4

    hipMemsetAsync(h0,  0, (size_t)NW * HDIM * sizeof(__hip_bfloat16), stream);
    hipMemsetAsync(cst, 0, (size_t)NW * HDIM * sizeof(float), stream);

    k_convert_whh<<<(G4H * HDIM) / (256 * 4), 256, 0, stream>>>(whh, wbf);
    k_char_proj<<<VCC, 256, 0, stream>>>(cemb, wih, bih, bhh, cproj);

    const __hip_bfloat16* hp = h0;
    __hip_bfloat16*       hn = h1buf;
    for (int t = 0; t < LSEQ; ++t) {
        k_lstm_step<<<256, 256, 0, stream>>>(hp, hn, cst, wbf, cproj, cidx, clen, t);
        const __hip_bfloat16* tmp = hn;
        hn = (__hip_bfloat16*)hp;
        hp = tmp;
    }

    k_sum_char<<<dim3(8, 8), 256, 0, stream>>>(hp, clen, pchar);
    k_sum_glove<<<dim3(5, 8), 256, 0, stream>>>(glove, widx, pglove);
    k_head<<<1, 512, 0, stream>>>(pglove, pchar, fc1W, fc1b, fc2W, fc2b, out);
}

// Round 2
// 1069.111 us; speedup vs baseline: 1.2984x; 1.2984x over previous
//
#include <hip/hip_runtime.h>
#include <hip/hip_cooperative_groups.h>
#include <hip/hip_bf16.h>
#include <stdint.h>
#include <stddef.h>

namespace cg = cooperative_groups;

#define NW    4096
#define LSEQ  24
#define HDIM  512
#define DWG   300
#define DCC   128
#define VCC   100
#define G4H   2048
#define CATD  812
#define HIDD  512
#define NOUT  5

typedef __bf16 bf16x8 __attribute__((ext_vector_type(8)));
typedef float  f32x16 __attribute__((ext_vector_type(16)));

__device__ __forceinline__ float frcp(float x) { return __builtin_amdgcn_rcpf(x); }
__device__ __forceinline__ float sigf(float x) { return frcp(1.0f + __expf(-x)); }
__device__ __forceinline__ float tanh_fast(float x) { return fmaf(2.0f, frcp(1.0f + __expf(-2.0f * x)), -1.0f); }

// ---------------- prep: char_proj[c][j] = char_embed[c,:] @ W_ih[j,:] + b_ih[j] + b_hh[j] ----
__global__ void k_char_proj(const float* __restrict__ cemb, const float* __restrict__ wih,
                            const float* __restrict__ bih, const float* __restrict__ bhh,
                            float* __restrict__ cproj) {
    __shared__ float emb[DCC];
    const int c = blockIdx.x;
    if (threadIdx.x < DCC) emb[threadIdx.x] = cemb[c * DCC + threadIdx.x];
    __syncthreads();
    for (int j = threadIdx.x; j < G4H; j += blockDim.x) {
        const float* w = wih + (size_t)j * DCC;
        float acc = bih[j] + bhh[j];
#pragma unroll 4
        for (int k = 0; k < DCC; ++k) acc = fmaf(emb[k], w[k], acc);
        cproj[(size_t)c * G4H + j] = acc;
    }
}

// ---------------- persistent LSTM: W_hh in LDS (swizzled bf16), c/h-frozen in VGPRs --------
// grid 256 blocks (16 rowgroups x 16 colgroups, XCD-aware), 512 threads = 8 waves.
// Wave w: rows r0..r0+31 (one 32x32 MFMA tile) x 4 gates x 32 h-cols, K=512.
__global__ void __launch_bounds__(512, 2) k_lstm_persist(
        const float* __restrict__ whh,       // [2048][512] f32
        const float* __restrict__ cproj,     // [100][2048] f32
        const int* __restrict__ cidx,        // [NW][LSEQ]
        const int* __restrict__ clen,        // [NW]
        __hip_bfloat16* __restrict__ hb0,    // [NW][512] bf16 (final h lands here)
        __hip_bfloat16* __restrict__ hb1) {
    extern __shared__ char lds[];            // 128 KB: [128 rows][1024 B] swizzled
    const int b = blockIdx.x;
    const int xcd = b & 7, slot = b >> 3;
    const int rg  = xcd * 2 + (slot >> 4);   // 0..15 (16 cg-blocks of a rg share an XCD)
    const int cgI = slot & 15;               // 0..15
    const int tid = threadIdx.x;
    const int wave = tid >> 6, lane = tid & 63;
    const int l31 = lane & 31, lhi = lane >> 5;

    // ---- stage W tile -> LDS once (f32 -> bf16, XOR-swizzled), 8192 x 16B chunks ----
    for (int c = tid; c < 8192; c += 512) {
        const int r = c >> 6;                                    // LDS row = g*32 + wcol
        const int j = ((r >> 5) << 9) + (cgI << 5) + (r & 31);   // W_hh row
        const float* src = whh + ((size_t)j << 9) + ((c & 63) << 3);
        const float4 f0 = *reinterpret_cast<const float4*>(src);
        const float4 f1 = *reinterpret_cast<const float4*>(src + 4);
        union { bf16x8 v; __hip_bfloat16 e[8]; } u;
        u.e[0] = __float2bfloat16(f0.x); u.e[1] = __float2bfloat16(f0.y);
        u.e[2] = __float2bfloat16(f0.z); u.e[3] = __float2bfloat16(f0.w);
        u.e[4] = __float2bfloat16(f1.x); u.e[5] = __float2bfloat16(f1.y);
        u.e[6] = __float2bfloat16(f1.z); u.e[7] = __float2bfloat16(f1.w);
        const int sb = ((c & 63) << 4) ^ ((r & 15) << 4);
        *reinterpret_cast<bf16x8*>(lds + (r << 10) + sb) = u.v;
    }
    __syncthreads();

    const int r0  = (rg << 8) + (wave << 5);
    const int col = (cgI << 5) + l31;
    const int xr  = (l31 & 15) << 4;

    int nrow[16]; int len16[16]; float creg[16]; float hold[16];
#pragma unroll
    for (int q = 0; q < 16; ++q) {
        const int rin = (q & 3) + ((q >> 2) << 3) + (lhi << 2);  // 32x32 C/D row map
        nrow[q] = r0 + rin;
        len16[q] = clen[r0 + rin];
        creg[q] = 0.0f; hold[q] = 0.0f;
    }

    const __hip_bfloat16* hp = hb0;
    __hip_bfloat16*       hn = hb1;
    cg::grid_group grid = cg::this_grid();

    for (int t = 0; t < LSEQ; ++t) {
        f32x16 acc[4] = {};
        if (t > 0) {
            const __hip_bfloat16* arow = hp + ((size_t)(r0 + l31) << 9) + (lhi << 3);
            const char* lb = lds + (l31 << 10);
#pragma unroll 4
            for (int k0 = 0; k0 < HDIM; k0 += 16) {
                const bf16x8 a = *reinterpret_cast<const bf16x8*>(arow + k0);
                const int kb = ((k0 << 1) + (lhi << 4)) ^ xr;
                const bf16x8 b0 = *reinterpret_cast<const bf16x8*>(lb + kb);
                const bf16x8 b1 = *reinterpret_cast<const bf16x8*>(lb + 32768 + kb);
                const bf16x8 b2 = *reinterpret_cast<const bf16x8*>(lb + 65536 + kb);
                const bf16x8 b3 = *reinterpret_cast<const bf16x8*>(lb + 98304 + kb);
                acc[0] = __builtin_amdgcn_mfma_f32_32x32x16_bf16(a, b0, acc[0], 0, 0, 0);
                acc[1] = __builtin_amdgcn_mfma_f32_32x32x16_bf16(a, b1, acc[1], 0, 0, 0);
                acc[2] = __builtin_amdgcn_mfma_f32_32x32x16_bf16(a, b2, acc[2], 0, 0, 0);
                acc[3] = __builtin_amdgcn_mfma_f32_32x32x16_bf16(a, b3, acc[3], 0, 0, 0);
            }
        }
#pragma unroll
        for (int q = 0; q < 16; ++q) {
            const int n  = nrow[q];
            const int ci = cidx[n * LSEQ + t];
            const float* cp = cproj + ((size_t)ci << 11) + col;
            const float gi = acc[0][q] + cp[0];
            const float gf = acc[1][q] + cp[512];
            const float gg = acc[2][q] + cp[1024];
            const float go = acc[3][q] + cp[1536];
            const float i_s = sigf(gi), f_s = sigf(gf);
            const float g_t = tanh_fast(gg), o_s = sigf(go);
            const float cn = f_s * creg[q] + i_s * g_t;
            const float hv = o_s * tanh_fast(cn);
            if (t < len16[q]) { creg[q] = cn; hold[q] = hv; }
            hn[((size_t)n << 9) + col] = __float2bfloat16(hold[q]);
        }
        grid.sync();
        const __hip_bfloat16* tmp = hn; hn = (__hip_bfloat16*)hp; hp = tmp;
    }
    // 24 steps: last write (t=23, odd) lands in hb0.
}

// ---------------- fallback path kernels (R1, known-correct) ----------------
__global__ void k_convert_whh(const float* __restrict__ w, __hip_bfloat16* __restrict__ o) {
    const int i = (blockIdx.x * blockDim.x + threadIdx.x) * 4;
    const float4 v = *reinterpret_cast<const float4*>(w + i);
    o[i + 0] = __float2bfloat16(v.x);
    o[i + 1] = __float2bfloat16(v.y);
    o[i + 2] = __float2bfloat16(v.z);
    o[i + 3] = __float2bfloat16(v.w);
}

__launch_bounds__(256, 1)
__global__ void k_lstm_step(const __hip_bfloat16* __restrict__ hprev,
                            __hip_bfloat16* __restrict__ hnext,
                            float* __restrict__ cstate,
                            const __hip_bfloat16* __restrict__ wbf,
                            const float* __restrict__ cproj,
                            const int* __restrict__ cidx,
                            const int* __restrict__ clen,
                            int t) {
    const int b = blockIdx.x;
    const int xcd = b & 7, slot = b >> 3;
    const int rg = xcd * 2 + (slot >> 4);
    const int cg_ = slot & 15;
    const int wave = threadIdx.x >> 6;
    const int lane = threadIdx.x & 63;
    const int l31 = lane & 31;
    const int lhi = lane >> 5;
    const int r0 = rg * 256 + wave * 64;
    const int c0 = cg_ * 32;
    f32x16 acc[2][4] = {};
    const __hip_bfloat16* arow0 = hprev + (size_t)(r0 + l31) * HDIM + lhi * 8;
    const __hip_bfloat16* arow1 = arow0 + 32 * HDIM;
    const __hip_bfloat16* bbase = wbf + (size_t)(c0 + l31) * HDIM + lhi * 8;
#pragma unroll 2
    for (int k0 = 0; k0 < HDIM; k0 += 16) {
        const bf16x8 a0 = *reinterpret_cast<const bf16x8*>(arow0 + k0);
        const bf16x8 a1 = *reinterpret_cast<const bf16x8*>(arow1 + k0);
        const bf16x8 b0 = *reinterpret_cast<const bf16x8*>(bbase + k0);
        const bf16x8 b1 = *reinterpret_cast<const bf16x8*>(bbase + 512 * HDIM + k0);
        const bf16x8 b2 = *reinterpret_cast<const bf16x8*>(bbase + 1024 * HDIM + k0);
        const bf16x8 b3 = *reinterpret_cast<const bf16x8*>(bbase + 1536 * HDIM + k0);
        acc[0][0] = __builtin_amdgcn_mfma_f32_32x32x16_bf16(a0, b0, acc[0][0], 0, 0, 0);
        acc[1][0] = __builtin_amdgcn_mfma_f32_32x32x16_bf16(a1, b0, acc[1][0], 0, 0, 0);
        acc[0][1] = __builtin_amdgcn_mfma_f32_32x32x16_bf16(a0, b1, acc[0][1], 0, 0, 0);
        acc[1][1] = __builtin_amdgcn_mfma_f32_32x32x16_bf16(a1, b1, acc[1][1], 0, 0, 0);
        acc[0][2] = __builtin_amdgcn_mfma_f32_32x32x16_bf16(a0, b2, acc[0][2], 0, 0, 0);
        acc[1][2] = __builtin_amdgcn_mfma_f32_32x32x16_bf16(a1, b2, acc[1][2], 0, 0, 0);
        acc[0][3] = __builtin_amdgcn_mfma_f32_32x32x16_bf16(a0, b3, acc[0][3], 0, 0, 0);
        acc[1][3] = __builtin_amdgcn_mfma_f32_32x32x16_bf16(a1, b3, acc[1][3], 0, 0, 0);
    }
    const int colh = c0 + l31;
#pragma unroll
    for (int rt = 0; rt < 2; ++rt) {
#pragma unroll
        for (int reg = 0; reg < 16; ++reg) {
            const int rin = (reg & 3) + 8 * (reg >> 2) + 4 * lhi;
            const int n = r0 + rt * 32 + rin;
            const int ci = cidx[n * LSEQ + t];
            const int len = clen[n];
            const float* cp = cproj + (size_t)ci * G4H + colh;
            const float gi = acc[rt][0][reg] + cp[0];
            const float gf = acc[rt][1][reg] + cp[512];
            const float gg = acc[rt][2][reg] + cp[1024];
            const float go = acc[rt][3][reg] + cp[1536];
            const size_t off = (size_t)n * HDIM + colh;
            const float c_old = cstate[off];
            const float i_s = sigf(gi);
            const float f_s = sigf(gf);
            const float g_t = tanh_fast(gg);
            const float o_s = sigf(go);
            const float c_new = f_s * c_old + i_s * g_t;
            const float h_new = o_s * tanh_fast(c_new);
            const bool valid = (t < len);
            if (valid) cstate[off] = c_new;
            hnext[off] = valid ? __float2bfloat16(h_new) : hprev[off];
        }
    }
}

// ---------------- masked column sums of final h (len>=2), 8x16 partial grid ----------------
__global__ void k_sum_char(const __hip_bfloat16* __restrict__ h, const int* __restrict__ clen,
                           float* __restrict__ pchar) {
    const int col = blockIdx.x * 64 + (threadIdx.x & 63);
    const int phase = threadIdx.x >> 6;
    const int nbase = blockIdx.y * 256;
    float s = 0.0f;
    for (int n = nbase + phase; n < nbase + 256; n += 4) {
        if (clen[n] >= 2) s += __bfloat162float(h[(size_t)n * HDIM + col]);
    }
    __shared__ float red[256];
    red[threadIdx.x] = s;
    __syncthreads();
    if (phase == 0) {
        pchar[blockIdx.y * HDIM + col] =
            red[threadIdx.x] + red[threadIdx.x + 64] + red[threadIdx.x + 128] + red[threadIdx.x + 192];
    }
}

// ---------------- glove gather column sums, 5x16 partial grid ----------------
__global__ void k_sum_glove(const float* __restrict__ gt, const int* __restrict__ widx,
                            float* __restrict__ pglove) {
    const int col = blockIdx.x * 64 + (threadIdx.x & 63);
    const int phase = threadIdx.x >> 6;
    const int nbase = blockIdx.y * 256;
    float s = 0.0f;
    if (col < DWG) {
        for (int n = nbase + phase; n < nbase + 256; n += 4) {
            s += gt[(size_t)widx[n] * DWG + col];
        }
    }
    __shared__ float red[256];
    red[threadIdx.x] = s;
    __syncthreads();
    if (phase == 0 && col < DWG) {
        pglove[blockIdx.y * DWG + col] =
            red[threadIdx.x] + red[threadIdx.x + 64] + red[threadIdx.x + 128] + red[threadIdx.x + 192];
    }
}

// ---------------- head: avg -> fc1 (64 blocks, 1 wave per output) -> fc2 ----------------
__global__ void k_avg(const float* __restrict__ pglove, const float* __restrict__ pchar,
                      float* __restrict__ avg) {
    const int i = blockIdx.x * 256 + threadIdx.x;
    if (i >= CATD) return;
    float s = 0.0f;
    if (i < DWG) {
        for (int r = 0; r < 16; ++r) s += pglove[r * DWG + i];
    } else {
        const int c = i - DWG;
        for (int r = 0; r < 16; ++r) s += pchar[r * HDIM + c];
    }
    avg[i] = s * (1.0f / 4096.0f);
}

__global__ void k_fc1(const float* __restrict__ avg, const float* __restrict__ W,
                      const float* __restrict__ bias, float* __restrict__ h1) {
    const int wave = threadIdx.x >> 6, lane = threadIdx.x & 63;
    const int j = blockIdx.x * 8 + wave;
    const float* w = W + (size_t)j * CATD;
    float s = 0.0f;
    for (int k = lane; k < CATD; k += 64) s += avg[k] * w[k];
#pragma unroll
    for (int o = 32; o > 0; o >>= 1) s += __shfl_down(s, o, 64);
    if (lane == 0) h1[j] = sigf(s + bias[j]);
}

__global__ void k_fc2(const float* __restrict__ h1, const float* __restrict__ W,
                      const float* __restrict__ bias, float* __restrict__ out) {
    const int wave = threadIdx.x >> 6, lane = threadIdx.x & 63;
    const float* w = W + (size_t)wave * HIDD;
    float s = 0.0f;
    for (int k = lane; k < HIDD; k += 64) s += h1[k] * w[k];
#pragma unroll
    for (int o = 32; o > 0; o >>= 1) s += __shfl_down(s, o, 64);
    if (lane == 0) out[wave] = s + bias[wave];
}

extern "C" void kernel_launch(void* const* d_in, const int* in_sizes, int n_in,
                              void* d_out, int out_size, void* d_ws, size_t ws_size,
                              hipStream_t stream) {
    (void)in_sizes; (void)n_in; (void)out_size; (void)ws_size;
    const int*   widx  = (const int*)d_in[0];
    const int*   cidx  = (const int*)d_in[1];
    const int*   clen  = (const int*)d_in[2];
    const float* glove = (const float*)d_in[3];
    const float* cemb  = (const float*)d_in[4];
    const float* wih   = (const float*)d_in[5];
    const float* whh   = (const float*)d_in[6];
    const float* bih   = (const float*)d_in[7];
    const float* bhh   = (const float*)d_in[8];
    const float* fc1W  = (const float*)d_in[9];
    const float* fc1b  = (const float*)d_in[10];
    const float* fc2W  = (const float*)d_in[11];
    const float* fc2b  = (const float*)d_in[12];
    float* out = (float*)d_out;

    char* ws = (char*)d_ws;
    float*          cproj  = (float*)(ws);                          // 800 KB
    __hip_bfloat16* hb0    = (__hip_bfloat16*)(ws + (1u << 20));    // 4 MB
    __hip_bfloat16* hb1    = (__hip_bfloat16*)(ws + (5u << 20));    // 4 MB
    float*          pchar  = (float*)(ws + (9u << 20));             // 32 KB
    float*          pglove = (float*)(ws + (9u << 20) + 32 * 1024); // 19 KB
    float*          avg    = (float*)(ws + (9u << 20) + 52 * 1024); // 3.2 KB
    float*          h1g    = (float*)(ws + (9u << 20) + 56 * 1024); // 2 KB
    __hip_bfloat16* wbf    = (__hip_bfloat16*)(ws + (9u << 20) + 64 * 1024);   // fallback, 2 MB
    float*          cst    = (float*)(ws + (11u << 20) + 256 * 1024);          // fallback, 8 MB

    k_char_proj<<<VCC, 256, 0, stream>>>(cemb, wih, bih, bhh, cproj);

    {
        const float* whh_ = whh;  const float* cproj_ = cproj;
        const int*   cidx_ = cidx; const int*  clen_ = clen;
        __hip_bfloat16* hb0_ = hb0; __hip_bfloat16* hb1_ = hb1;
        void* args[6] = { &whh_, &cproj_, &cidx_, &clen_, &hb0_, &hb1_ };
        hipError_t ce = hipLaunchCooperativeKernel(k_lstm_persist, dim3(256), dim3(512),
                                                   args, 131072u, stream);
        if (ce != hipSuccess) {
            // fallback: R1 per-step path (known correct)
            hipMemsetAsync(hb0, 0, (size_t)NW * HDIM * sizeof(__hip_bfloat16), stream);
            hipMemsetAsync(cst, 0, (size_t)NW * HDIM * sizeof(float), stream);
            k_convert_whh<<<(G4H * HDIM) / (256 * 4), 256, 0, stream>>>(whh, wbf);
            const __hip_bfloat16* hp = hb0;
            __hip_bfloat16*       hn = hb1;
            for (int t = 0; t < LSEQ; ++t) {
                k_lstm_step<<<256, 256, 0, stream>>>(hp, hn, cst, wbf, cproj, cidx, clen, t);
                const __hip_bfloat16* tmp = hn;
                hn = (__hip_bfloat16*)hp;
                hp = tmp;
            }
        }
    }

    // final h (both paths) is in hb0
    k_sum_char<<<dim3(8, 16), 256, 0, stream>>>(hb0, clen, pchar);
    k_sum_glove<<<dim3(5, 16), 256, 0, stream>>>(glove, widx, pglove);
    k_avg<<<4, 256, 0, stream>>>(pglove, pchar, avg);
    k_fc1<<<64, 512, 0, stream>>>(avg, fc1W, fc1b, h1g);
    k_fc2<<<1, 320, 0, stream>>>(h1g, fc2W, fc2b, out);
}

// Round 3
// 631.373 us; speedup vs baseline: 2.1985x; 1.6933x over previous
//
#include <hip/hip_runtime.h>
#include <hip/hip_bf16.h>
#include <stdint.h>
#include <stddef.h>

#define NW    4096
#define LSEQ  24
#define HDIM  512
#define DWG   300
#define DCC   128
#define VCC   100
#define G4H   2048
#define CATD  812
#define HIDD  512
#define NOUT  5
#define NBLK  128   // LSTM blocks (32 rows each, no cross-block deps)
#define RB    32

typedef __bf16 bf16x8 __attribute__((ext_vector_type(8)));
typedef float  f32x16 __attribute__((ext_vector_type(16)));

__device__ __forceinline__ float frcp(float x) { return __builtin_amdgcn_rcpf(x); }
__device__ __forceinline__ float sigf(float x) { return frcp(1.0f + __expf(-x)); }
__device__ __forceinline__ float tanh_fast(float x) { return fmaf(2.0f, frcp(1.0f + __expf(-2.0f * x)), -1.0f); }

// ---- retile W_hh f32 [2048][512] -> bf16 k-panel-major: wt[((k>>4)*2048 + j)*16 + (k&15)] ----
// B-fragment loads become 1KB-contiguous per wave per (gate, kstep).
__global__ void k_convert_wtile(const float* __restrict__ whh, __hip_bfloat16* __restrict__ wt) {
    const int tid = blockIdx.x * 256 + threadIdx.x;   // 65536 threads: (j, panel)
    const int j = tid >> 5, p = tid & 31;
    const float* src = whh + (size_t)j * HDIM + p * 16;
    union { bf16x8 v[2]; __hip_bfloat16 e[16]; } u;
#pragma unroll
    for (int i = 0; i < 4; ++i) {
        const float4 f = *reinterpret_cast<const float4*>(src + i * 4);
        u.e[i * 4 + 0] = __float2bfloat16(f.x);
        u.e[i * 4 + 1] = __float2bfloat16(f.y);
        u.e[i * 4 + 2] = __float2bfloat16(f.z);
        u.e[i * 4 + 3] = __float2bfloat16(f.w);
    }
    bf16x8* dst = reinterpret_cast<bf16x8*>(wt + (((size_t)p * G4H + j) << 4));
    dst[0] = u.v[0];
    dst[1] = u.v[1];
}

// ---- char_proj[c][j] = char_embed[c,:] @ W_ih[j,:] + b_ih[j] + b_hh[j]  (bf16 out) ----
__global__ void k_char_proj(const float* __restrict__ cemb, const float* __restrict__ wih,
                            const float* __restrict__ bih, const float* __restrict__ bhh,
                            __hip_bfloat16* __restrict__ cproj) {
    __shared__ float emb[DCC];
    const int c = blockIdx.x;
    if (threadIdx.x < DCC) emb[threadIdx.x] = cemb[c * DCC + threadIdx.x];
    __syncthreads();
    for (int j = threadIdx.x; j < G4H; j += blockDim.x) {
        const float* w = wih + (size_t)j * DCC;
        float acc = bih[j] + bhh[j];
#pragma unroll 4
        for (int k = 0; k < DCC; ++k) acc = fmaf(emb[k], w[k], acc);
        cproj[(size_t)c * G4H + j] = __float2bfloat16(acc);
    }
}

// ---- LSTM: block owns 32 rows for all 24 steps. h in swizzled LDS dbuf + regs, c in regs.
// 128 blocks x 512 threads (8 waves). Wave w, pass p: hcol-tile hc=2w+p, all 4 gates, K=512.
// W streamed from L2 (k-panel tiled). Only sync: one __syncthreads per step.
__global__ void __launch_bounds__(512, 2) k_lstm_block(
        const __hip_bfloat16* __restrict__ wt,     // [32 panels][2048][16] bf16
        const __hip_bfloat16* __restrict__ cproj,  // [100][2048] bf16
        const int* __restrict__ cidx,              // [NW][LSEQ]
        const int* __restrict__ clen,              // [NW]
        float* __restrict__ pchar) {               // [NBLK][512] partial col sums
    extern __shared__ char lds[];                  // 2 x 32KB h buffers, XOR-swizzled
    const int b = blockIdx.x;
    const int tid = threadIdx.x;
    const int w = tid >> 6, lane = tid & 63;
    const int l31 = lane & 31, lhi = lane >> 5;
    const int n0 = b * RB;

    {   // zero both h buffers
        int4 z = {0, 0, 0, 0};
        int4* pz = (int4*)lds;
#pragma unroll
        for (int i = 0; i < 8; ++i) pz[i * 512 + tid] = z;
    }

    int len16[16];
#pragma unroll
    for (int q = 0; q < 16; ++q) {
        const int rin = (q & 3) + ((q >> 2) << 3) + (lhi << 2);
        len16[q] = clen[n0 + rin];
    }
    float cs[2][16], hs[2][16];
#pragma unroll
    for (int p = 0; p < 2; ++p)
#pragma unroll
        for (int q = 0; q < 16; ++q) { cs[p][q] = 0.0f; hs[p][q] = 0.0f; }

    const int xr = (l31 & 15) << 4;
    __syncthreads();

    for (int t = 0; t < LSEQ; ++t) {
        const int cur = t & 1;
        const char* rl = lds + (cur << 15) + (l31 << 10);   // A: row l31 of current buf
        char* wl = lds + ((cur ^ 1) << 15);                  // write next buf

        int ci16[16];
#pragma unroll
        for (int q = 0; q < 16; ++q) {
            const int rin = (q & 3) + ((q >> 2) << 3) + (lhi << 2);
            ci16[q] = cidx[(n0 + rin) * LSEQ + t];
        }

#pragma unroll
        for (int p = 0; p < 2; ++p) {
            const int hc = 2 * w + p;
            f32x16 acc[4] = {};
            if (t > 0) {
                const __hip_bfloat16* wb = wt + (((size_t)(hc * 32 + l31)) << 4) + (lhi << 3);
#pragma unroll 4
                for (int kp = 0; kp < 32; ++kp) {
                    const bf16x8 a = *reinterpret_cast<const bf16x8*>(
                        rl + (((kp << 5) | (lhi << 4)) ^ xr));
                    const size_t pb = (size_t)kp * (G4H * 16);
                    const bf16x8 b0 = *reinterpret_cast<const bf16x8*>(wb + pb);
                    const bf16x8 b1 = *reinterpret_cast<const bf16x8*>(wb + pb + 8192);
                    const bf16x8 b2 = *reinterpret_cast<const bf16x8*>(wb + pb + 16384);
                    const bf16x8 b3 = *reinterpret_cast<const bf16x8*>(wb + pb + 24576);
                    acc[0] = __builtin_amdgcn_mfma_f32_32x32x16_bf16(a, b0, acc[0], 0, 0, 0);
                    acc[1] = __builtin_amdgcn_mfma_f32_32x32x16_bf16(a, b1, acc[1], 0, 0, 0);
                    acc[2] = __builtin_amdgcn_mfma_f32_32x32x16_bf16(a, b2, acc[2], 0, 0, 0);
                    acc[3] = __builtin_amdgcn_mfma_f32_32x32x16_bf16(a, b3, acc[3], 0, 0, 0);
                }
            }
            const int colh = hc * 32 + l31;
#pragma unroll
            for (int q = 0; q < 16; ++q) {
                const int rin = (q & 3) + ((q >> 2) << 3) + (lhi << 2);
                const __hip_bfloat16* cp = cproj + ((size_t)ci16[q] << 11) + colh;
                const float gi = acc[0][q] + __bfloat162float(cp[0]);
                const float gf = acc[1][q] + __bfloat162float(cp[512]);
                const float gg = acc[2][q] + __bfloat162float(cp[1024]);
                const float go = acc[3][q] + __bfloat162float(cp[1536]);
                const float i_s = sigf(gi), f_s = sigf(gf);
                const float g_t = tanh_fast(gg), o_s = sigf(go);
                const float cn = f_s * cs[p][q] + i_s * g_t;
                const float hv = o_s * tanh_fast(cn);
                if (t < len16[q]) { cs[p][q] = cn; hs[p][q] = hv; }
                *reinterpret_cast<__hip_bfloat16*>(
                    wl + (rin << 10) + (((colh << 1)) ^ ((rin & 15) << 4))) =
                    __float2bfloat16(hs[p][q]);
            }
        }
        __syncthreads();
    }

    // block-local masked column partial sums straight from registers (f32 precision)
#pragma unroll
    for (int p = 0; p < 2; ++p) {
        float s = 0.0f;
#pragma unroll
        for (int q = 0; q < 16; ++q) s += (len16[q] >= 2) ? hs[p][q] : 0.0f;
        s += __shfl_xor(s, 32, 64);
        if (lhi == 0) pchar[b * HDIM + (2 * w + p) * 32 + l31] = s;
    }
}

// ---- glove gather column sums, 5x16 partial grid ----
__global__ void k_sum_glove(const float* __restrict__ gt, const int* __restrict__ widx,
                            float* __restrict__ pglove) {
    const int col = blockIdx.x * 64 + (threadIdx.x & 63);
    const int phase = threadIdx.x >> 6;
    const int nbase = blockIdx.y * 256;
    float s = 0.0f;
    if (col < DWG) {
        for (int n = nbase + phase; n < nbase + 256; n += 4) {
            s += gt[(size_t)widx[n] * DWG + col];
        }
    }
    __shared__ float red[256];
    red[threadIdx.x] = s;
    __syncthreads();
    if (phase == 0 && col < DWG) {
        pglove[blockIdx.y * DWG + col] =
            red[threadIdx.x] + red[threadIdx.x + 64] + red[threadIdx.x + 128] + red[threadIdx.x + 192];
    }
}

// ---- combine partials -> avg vector ----
__global__ void k_avg(const float* __restrict__ pglove, const float* __restrict__ pchar,
                      float* __restrict__ avg) {
    const int i = blockIdx.x * 256 + threadIdx.x;
    if (i >= CATD) return;
    float s = 0.0f;
    if (i < DWG) {
        for (int r = 0; r < 16; ++r) s += pglove[r * DWG + i];
    } else {
        const int c = i - DWG;
        for (int r = 0; r < NBLK; ++r) s += pchar[r * HDIM + c];
    }
    avg[i] = s * (1.0f / 4096.0f);
}

__global__ void k_fc1(const float* __restrict__ avg, const float* __restrict__ W,
                      const float* __restrict__ bias, float* __restrict__ h1) {
    const int wave = threadIdx.x >> 6, lane = threadIdx.x & 63;
    const int j = blockIdx.x * 8 + wave;
    const float* w = W + (size_t)j * CATD;
    float s = 0.0f;
    for (int k = lane; k < CATD; k += 64) s += avg[k] * w[k];
#pragma unroll
    for (int o = 32; o > 0; o >>= 1) s += __shfl_down(s, o, 64);
    if (lane == 0) h1[j] = sigf(s + bias[j]);
}

__global__ void k_fc2(const float* __restrict__ h1, const float* __restrict__ W,
                      const float* __restrict__ bias, float* __restrict__ out) {
    const int wave = threadIdx.x >> 6, lane = threadIdx.x & 63;
    const float* w = W + (size_t)wave * HIDD;
    float s = 0.0f;
    for (int k = lane; k < HIDD; k += 64) s += h1[k] * w[k];
#pragma unroll
    for (int o = 32; o > 0; o >>= 1) s += __shfl_down(s, o, 64);
    if (lane == 0) out[wave] = s + bias[wave];
}

extern "C" void kernel_launch(void* const* d_in, const int* in_sizes, int n_in,
                              void* d_out, int out_size, void* d_ws, size_t ws_size,
                              hipStream_t stream) {
    (void)in_sizes; (void)n_in; (void)out_size; (void)ws_size;
    const int*   widx  = (const int*)d_in[0];
    const int*   cidx  = (const int*)d_in[1];
    const int*   clen  = (const int*)d_in[2];
    const float* glove = (const float*)d_in[3];
    const float* cemb  = (const float*)d_in[4];
    const float* wih   = (const float*)d_in[5];
    const float* whh   = (const float*)d_in[6];
    const float* bih   = (const float*)d_in[7];
    const float* bhh   = (const float*)d_in[8];
    const float* fc1W  = (const float*)d_in[9];
    const float* fc1b  = (const float*)d_in[10];
    const float* fc2W  = (const float*)d_in[11];
    const float* fc2b  = (const float*)d_in[12];
    float* out = (float*)d_out;

    char* ws = (char*)d_ws;
    __hip_bfloat16* wt     = (__hip_bfloat16*)(ws);                         // 2 MB
    __hip_bfloat16* cproj  = (__hip_bfloat16*)(ws + (2u << 20));            // 400 KB
    float*          pchar  = (float*)(ws + (2u << 20) + (512u << 10));      // 256 KB
    float*          pglove = (float*)(ws + (2u << 20) + (768u << 10));      // 19.2 KB
    float*          avg    = (float*)(ws + (2u << 20) + (800u << 10));      // 3.2 KB
    float*          h1g    = (float*)(ws + (2u << 20) + (808u << 10));      // 2 KB

    k_convert_wtile<<<256, 256, 0, stream>>>(whh, wt);
    k_char_proj<<<VCC, 256, 0, stream>>>(cemb, wih, bih, bhh, cproj);
    k_lstm_block<<<NBLK, 512, 65536, stream>>>(wt, cproj, cidx, clen, pchar);
    k_sum_glove<<<dim3(5, 16), 256, 0, stream>>>(glove, widx, pglove);
    k_avg<<<4, 256, 0, stream>>>(pglove, pchar, avg);
    k_fc1<<<64, 512, 0, stream>>>(avg, fc1W, fc1b, h1g);
    k_fc2<<<1, 320, 0, stream>>>(h1g, fc2W, fc2b, out);
}